// Round 1
// baseline (890.913 us; speedup 1.0000x reference)
//
#include <hip/hip_runtime.h>
#include <hip/hip_bf16.h>

#define M_NODES 100000
#define N_EDGES 1600000
#define K_IN 512
#define N_OUT 256

typedef short bf16x8 __attribute__((ext_vector_type(8)));
typedef float f32x4 __attribute__((ext_vector_type(4)));

__device__ inline short f2bf(float f) {
  union { float f; unsigned u; } x; x.f = f;
  unsigned r = x.u + 0x7FFFu + ((x.u >> 16) & 1u);
  return (short)(r >> 16);
}

// weight [512][256] f32 -> Wt bf16 [256][512] (transposed, so B-frag loads are contiguous)
__global__ void prep_w_kernel(const float* __restrict__ w, short* __restrict__ wt) {
  int idx = blockIdx.x * 256 + threadIdx.x;   // 131072 total
  int k = idx >> 8, n = idx & 255;
  wt[n * K_IN + k] = f2bf(w[idx]);
}

// row_ptr[r] = lower_bound(row, r) over sorted row[] (COO -> CSR)
__global__ void build_rp_kernel(const int* __restrict__ row, int* __restrict__ rp) {
  int r = blockIdx.x * 256 + threadIdx.x;
  if (r > M_NODES) return;
  int lo = 0, hi = N_EDGES;
  while (lo < hi) {
    int mid = (lo + hi) >> 1;
    if (row[mid] < r) lo = mid + 1; else hi = mid;
  }
  rp[r] = lo;
}

// H = tanh(A @ W), A fp32 [M,512], Wt bf16 [256][512]; block = 64 rows x all 256 cols
__global__ __launch_bounds__(256) void gemm_tanh_kernel(
    const float* __restrict__ A, const short* __restrict__ Wt,
    float* __restrict__ H) {
  __shared__ __align__(16) short As[64 * 32];    // [m][k] bf16
  __shared__ __align__(16) short Bs[256 * 32];   // [n][k] bf16
  const int tid = threadIdx.x;
  const int wave = tid >> 6, lane = tid & 63;
  const int quad = lane >> 4, l16 = lane & 15;
  const int row0 = blockIdx.x * 64;

  f32x4 acc[16];
  #pragma unroll
  for (int i = 0; i < 16; ++i) acc[i] = (f32x4){0.f, 0.f, 0.f, 0.f};

  const int ra = tid >> 2;        // 0..63 : A tile row
  const int ka = (tid & 3) * 8;   // 0,8,16,24 : k offset
  const int gr = min(row0 + ra, M_NODES - 1);

  for (int k0 = 0; k0 < K_IN; k0 += 32) {
    // stage A: 64x32 fp32 -> bf16
    float4 a0 = *(const float4*)&A[(size_t)gr * K_IN + k0 + ka];
    float4 a1 = *(const float4*)&A[(size_t)gr * K_IN + k0 + ka + 4];
    union { short s[8]; int4 v; } u;
    u.s[0] = f2bf(a0.x); u.s[1] = f2bf(a0.y); u.s[2] = f2bf(a0.z); u.s[3] = f2bf(a0.w);
    u.s[4] = f2bf(a1.x); u.s[5] = f2bf(a1.y); u.s[6] = f2bf(a1.z); u.s[7] = f2bf(a1.w);
    *(int4*)&As[ra * 32 + ka] = u.v;
    // stage B: 256 n-rows x 32 k, already bf16+transposed in global
    #pragma unroll
    for (int j = 0; j < 4; ++j) {
      int n = j * 64 + ra;
      int4 bv = *(const int4*)&Wt[(size_t)n * K_IN + k0 + ka];
      *(int4*)&Bs[n * 32 + ka] = bv;
    }
    __syncthreads();
    // A-frag: m = lane&15, k = quad*8 + j
    bf16x8 af = *(const bf16x8*)&As[(wave * 16 + l16) * 32 + quad * 8];
    #pragma unroll
    for (int nt = 0; nt < 16; ++nt) {
      // B-frag: n = lane&15, k = quad*8 + j  (Bs is [n][k])
      bf16x8 bfr = *(const bf16x8*)&Bs[(nt * 16 + l16) * 32 + quad * 8];
      acc[nt] = __builtin_amdgcn_mfma_f32_16x16x32_bf16(af, bfr, acc[nt], 0, 0, 0);
    }
    __syncthreads();
  }
  // epilogue: C/D layout col = lane&15, row = quad*4 + reg
  #pragma unroll
  for (int nt = 0; nt < 16; ++nt) {
    #pragma unroll
    for (int r = 0; r < 4; ++r) {
      int row = row0 + wave * 16 + quad * 4 + r;
      if (row < M_NODES) {
        int c = nt * 16 + l16;
        H[(size_t)row * N_OUT + c] = tanhf(acc[nt][r]);
      }
    }
  }
}

// y[i,:] = sum_e vals[e] * x[col[e],:] for e in [rp[i], rp[i+1]).  One wave per row,
// lane holds float4 -> each edge gather reads a full contiguous 1KB row.
__global__ __launch_bounds__(256) void spmm_kernel(
    const int* __restrict__ rp, const int* __restrict__ colv,
    const float* __restrict__ vals, const float* __restrict__ x,
    float* __restrict__ y) {
  int w = (blockIdx.x * 256 + threadIdx.x) >> 6;
  int lane = threadIdx.x & 63;
  int i = __builtin_amdgcn_readfirstlane(w);   // wave-uniform row index -> SGPR
  int s = rp[i], e = rp[i + 1];
  float4 acc = {0.f, 0.f, 0.f, 0.f};
  const float4* x4 = (const float4*)x;
  for (int t = s; t < e; ++t) {
    float v = vals[t];
    int c = colv[t];
    float4 xv = x4[(size_t)c * 64 + lane];
    acc.x += v * xv.x; acc.y += v * xv.y; acc.z += v * xv.z; acc.w += v * xv.w;
  }
  ((float4*)y)[(size_t)i * 64 + lane] = acc;
}

extern "C" void kernel_launch(void* const* d_in, const int* in_sizes, int n_in,
                              void* d_out, int out_size, void* d_ws, size_t ws_size,
                              hipStream_t stream) {
  const float* features = (const float*)d_in[0];
  const float* weight   = (const float*)d_in[1];
  const int*   row      = (const int*)d_in[2];
  const int*   col      = (const int*)d_in[3];
  const float* vals     = (const float*)d_in[4];
  float* out = (float*)d_out;

  char* ws = (char*)d_ws;
  const size_t HBYTES = (size_t)M_NODES * N_OUT * 4;     // 102,400,000
  const size_t RPBYTES = 400016;                          // 100001 ints, padded to 16
  const size_t WTBYTES = 262144;                          // 131072 bf16
  float* H  = (float*)ws;
  int*   rp = (int*)(ws + HBYTES);
  short* Wt = (short*)(ws + HBYTES + RPBYTES);
  float* B1 = (float*)(ws + HBYTES + RPBYTES + WTBYTES);
  bool two_buf = ws_size >= 2 * HBYTES + RPBYTES + WTBYTES;

  prep_w_kernel<<<512, 256, 0, stream>>>(weight, Wt);
  build_rp_kernel<<<(M_NODES + 1 + 255) / 256, 256, 0, stream>>>(row, rp);
  gemm_tanh_kernel<<<(M_NODES + 63) / 64, 256, 0, stream>>>(features, Wt, H);

  float* x1 = two_buf ? B1 : out;
  spmm_kernel<<<25000, 256, 0, stream>>>(rp, col, vals, H, x1);
  float* x2 = two_buf ? out : H;
  spmm_kernel<<<25000, 256, 0, stream>>>(rp, col, vals, x1, x2);
  if (!two_buf) {
    hipMemcpyAsync(out, H, HBYTES, hipMemcpyDeviceToDevice, stream);
  }
}

// Round 2
// 628.793 us; speedup vs baseline: 1.4169x; 1.4169x over previous
//
#include <hip/hip_runtime.h>
#include <hip/hip_bf16.h>

#define M_NODES 100000
#define N_EDGES 1600000
#define K_IN 512
#define N_OUT 256

typedef short bf16x8 __attribute__((ext_vector_type(8)));
typedef float f32x4 __attribute__((ext_vector_type(4)));

#define GLOBAL_AS __attribute__((address_space(1)))
#define LDS_AS __attribute__((address_space(3)))

__device__ inline unsigned short f2bf_u(float f) {
  union { float f; unsigned u; } x; x.f = f;
  unsigned r = x.u + 0x7FFFu + ((x.u >> 16) & 1u);
  return (unsigned short)(r >> 16);
}
__device__ inline float bfu2f(unsigned short h) {
  union { unsigned u; float f; } x; x.u = ((unsigned)h) << 16;
  return x.f;
}

// weight [512][256] f32 -> Wt bf16 [256][512] (transposed: B-frag k-contiguous)
__global__ void prep_w_kernel(const float* __restrict__ w, short* __restrict__ wt) {
  int idx = blockIdx.x * 256 + threadIdx.x;   // 131072 total
  int k = idx >> 8, n = idx & 255;
  wt[n * K_IN + k] = (short)f2bf_u(w[idx]);
}

// row_ptr[r] = lower_bound(row, r) over sorted row[] (COO -> CSR)
__global__ void build_rp_kernel(const int* __restrict__ row, int* __restrict__ rp) {
  int r = blockIdx.x * 256 + threadIdx.x;
  if (r > M_NODES) return;
  int lo = 0, hi = N_EDGES;
  while (lo < hi) {
    int mid = (lo + hi) >> 1;
    if (row[mid] < r) lo = mid + 1; else hi = mid;
  }
  rp[r] = lo;
}

// H = bf16(tanh(A @ W)). A fp32 [M,512], Wt bf16 [256][512].
// Block: 256 thr, M_TILE=64, N=256, BK=64. LDS XOR-swizzled in 16B chunks:
// element [r][k] lives at r*ROWB + ((k/8) ^ (r&7))*8 shorts.
__global__ __launch_bounds__(256) void gemm_tanh_kernel(
    const float* __restrict__ A, const short* __restrict__ Wt,
    unsigned short* __restrict__ H) {
  __shared__ __align__(16) short As[64 * 64];    // 8KB  (rows 0..63, 64 k)
  __shared__ __align__(16) short Bs[256 * 64];   // 32KB (n 0..255, 64 k)
  const int tid = threadIdx.x;
  const int wave = tid >> 6, lane = tid & 63;
  const int quad = lane >> 4, l16 = lane & 15;
  const int row0 = blockIdx.x * 64;

  f32x4 acc[16];
  #pragma unroll
  for (int i = 0; i < 16; ++i) acc[i] = (f32x4){0.f, 0.f, 0.f, 0.f};

  const int ra = tid >> 2;             // 0..63 : A tile row
  const int kb = (tid & 3) << 4;       // 0,16,32,48 : k offset (floats)
  const int gr = min(row0 + ra, M_NODES - 1);
  const float* Arow = A + (size_t)gr * K_IN;

  for (int k0 = 0; k0 < K_IN; k0 += 64) {
    // --- B: async global->LDS, swizzled. wave covers n in [64*wave, 64*wave+64)
    #pragma unroll
    for (int it = 0; it < 8; ++it) {
      int g = wave * 512 + it * 64 + lane;     // chunk id in Bs
      int n = g >> 3, phys = g & 7;
      int j = phys ^ (n & 7);                  // logical k-chunk
      const short* gp = Wt + (size_t)n * K_IN + k0 + j * 8;
      __builtin_amdgcn_global_load_lds(
          (GLOBAL_AS const void*)gp,
          (LDS_AS void*)&Bs[(wave * 512 + it * 64) * 8],
          16, 0, 0);
    }
    // --- A: 4 float4 -> 16 bf16 -> 2 swizzled chunk writes
    float4 a0 = *(const float4*)&Arow[k0 + kb];
    float4 a1 = *(const float4*)&Arow[k0 + kb + 4];
    float4 a2 = *(const float4*)&Arow[k0 + kb + 8];
    float4 a3 = *(const float4*)&Arow[k0 + kb + 12];
    union { unsigned short s[16]; int4 v[2]; } u;
    u.s[0]=f2bf_u(a0.x); u.s[1]=f2bf_u(a0.y); u.s[2]=f2bf_u(a0.z); u.s[3]=f2bf_u(a0.w);
    u.s[4]=f2bf_u(a1.x); u.s[5]=f2bf_u(a1.y); u.s[6]=f2bf_u(a1.z); u.s[7]=f2bf_u(a1.w);
    u.s[8]=f2bf_u(a2.x); u.s[9]=f2bf_u(a2.y); u.s[10]=f2bf_u(a2.z); u.s[11]=f2bf_u(a2.w);
    u.s[12]=f2bf_u(a3.x); u.s[13]=f2bf_u(a3.y); u.s[14]=f2bf_u(a3.z); u.s[15]=f2bf_u(a3.w);
    int lc0 = kb >> 3;                         // logical chunk of first 8 bf16
    #pragma unroll
    for (int c = 0; c < 2; ++c) {
      int phys = (lc0 + c) ^ (ra & 7);
      *(int4*)&As[ra * 64 + phys * 8] = u.v[c];
    }
    __syncthreads();
    // --- MFMA: A-frag m=l16,k=quad*8+j ; B-frag n=l16,k=quad*8+j ; swizzled reads
    const int r = wave * 16 + l16;
    #pragma unroll
    for (int kstep = 0; kstep < 2; ++kstep) {
      int lc = kstep * 4 + quad;
      bf16x8 af = *(const bf16x8*)&As[r * 64 + (lc ^ (r & 7)) * 8];
      #pragma unroll
      for (int nt = 0; nt < 16; ++nt) {
        int n = nt * 16 + l16;
        bf16x8 bfr = *(const bf16x8*)&Bs[n * 64 + (lc ^ (n & 7)) * 8];
        acc[nt] = __builtin_amdgcn_mfma_f32_16x16x32_bf16(af, bfr, acc[nt], 0, 0, 0);
      }
    }
    __syncthreads();
  }
  // epilogue: C/D row=quad*4+reg, col=l16 ; store bf16
  #pragma unroll
  for (int nt = 0; nt < 16; ++nt) {
    #pragma unroll
    for (int rr = 0; rr < 4; ++rr) {
      int row = row0 + wave * 16 + quad * 4 + rr;
      if (row < M_NODES) {
        H[(size_t)row * N_OUT + nt * 16 + l16] = f2bf_u(tanhf(acc[nt][rr]));
      }
    }
  }
}

// y[i,:] = sum_e vals[e]*x[col[e],:], x bf16 [M,256]. One wave/row; lane holds
// 4 features (8B/edge/lane -> full 512B row per edge, coalesced).
__global__ __launch_bounds__(256) void spmm_bf_bf(
    const int* __restrict__ rp, const int* __restrict__ colv,
    const float* __restrict__ vals, const unsigned short* __restrict__ x,
    unsigned short* __restrict__ y) {
  int w = (blockIdx.x * 256 + threadIdx.x) >> 6;
  int lane = threadIdx.x & 63;
  int i = __builtin_amdgcn_readfirstlane(w);
  int s = rp[i], e = rp[i + 1];
  float a0 = 0.f, a1 = 0.f, a2 = 0.f, a3 = 0.f;
  for (int t = s; t < e; ++t) {
    float v = vals[t];
    int c = colv[t];
    ushort4 xv = *(const ushort4*)(x + (size_t)c * N_OUT + lane * 4);
    a0 += v * bfu2f(xv.x); a1 += v * bfu2f(xv.y);
    a2 += v * bfu2f(xv.z); a3 += v * bfu2f(xv.w);
  }
  ushort4 o;
  o.x = f2bf_u(a0); o.y = f2bf_u(a1); o.z = f2bf_u(a2); o.w = f2bf_u(a3);
  *(ushort4*)(y + (size_t)i * N_OUT + lane * 4) = o;
}

// same but f32 output (final layer writes d_out)
__global__ __launch_bounds__(256) void spmm_bf_f32(
    const int* __restrict__ rp, const int* __restrict__ colv,
    const float* __restrict__ vals, const unsigned short* __restrict__ x,
    float* __restrict__ y) {
  int w = (blockIdx.x * 256 + threadIdx.x) >> 6;
  int lane = threadIdx.x & 63;
  int i = __builtin_amdgcn_readfirstlane(w);
  int s = rp[i], e = rp[i + 1];
  float a0 = 0.f, a1 = 0.f, a2 = 0.f, a3 = 0.f;
  for (int t = s; t < e; ++t) {
    float v = vals[t];
    int c = colv[t];
    ushort4 xv = *(const ushort4*)(x + (size_t)c * N_OUT + lane * 4);
    a0 += v * bfu2f(xv.x); a1 += v * bfu2f(xv.y);
    a2 += v * bfu2f(xv.z); a3 += v * bfu2f(xv.w);
  }
  float4 o = {a0, a1, a2, a3};
  *(float4*)(y + (size_t)i * N_OUT + lane * 4) = o;
}

extern "C" void kernel_launch(void* const* d_in, const int* in_sizes, int n_in,
                              void* d_out, int out_size, void* d_ws, size_t ws_size,
                              hipStream_t stream) {
  const float* features = (const float*)d_in[0];
  const float* weight   = (const float*)d_in[1];
  const int*   row      = (const int*)d_in[2];
  const int*   col      = (const int*)d_in[3];
  const float* vals     = (const float*)d_in[4];
  float* out = (float*)d_out;

  char* ws = (char*)d_ws;
  const size_t HB = (size_t)M_NODES * N_OUT * 2;   // 51,200,000 bf16 H
  const size_t RPB = 400016;                        // 100001 ints padded
  unsigned short* H  = (unsigned short*)ws;
  unsigned short* y1 = (unsigned short*)(ws + HB);
  int*   rp = (int*)(ws + 2 * HB);
  short* Wt = (short*)(ws + 2 * HB + RPB);
  // total need: 2*51.2MB + 400016 + 262144 = 103,062,160 B (== round-1 min, fits)

  prep_w_kernel<<<512, 256, 0, stream>>>(weight, Wt);
  build_rp_kernel<<<(M_NODES + 1 + 255) / 256, 256, 0, stream>>>(row, rp);
  gemm_tanh_kernel<<<(M_NODES + 63) / 64, 256, 0, stream>>>(features, Wt, H);
  spmm_bf_bf<<<25000, 256, 0, stream>>>(rp, col, vals, H, y1);
  spmm_bf_f32<<<25000, 256, 0, stream>>>(rp, col, vals, y1, out);
}